// Round 5
// baseline (290.927 us; speedup 1.0000x reference)
//
#include <hip/hip_runtime.h>
#include <hip/hip_bf16.h>

// Problem constants (fixed by reference)
#define B_ 4
#define S_ 2048
#define D_ 1024
#define H_ 16
#define DK_ 64

typedef __attribute__((ext_vector_type(8))) short short8;
typedef __attribute__((ext_vector_type(4))) float floatx4;
typedef __attribute__((ext_vector_type(16))) float floatx16;
typedef __attribute__((ext_vector_type(4))) unsigned int uint4v;

#define QSCL 0.1803368801111204f  // log2(e)/sqrt(DK): folded into Q in GEMM epilogue

// round-to-nearest-even f32 -> bf16 bits
static __device__ __forceinline__ unsigned short f2bf(float f) {
    unsigned int u = __float_as_uint(f);
    u += 0x7fffu + ((u >> 16) & 1u);
    return (unsigned short)(u >> 16);
}

// pack two f32 -> bf16x2, round-nearest-ties-up via v_perm_b32 (3 VALU ops) [proven]
static __device__ __forceinline__ unsigned int pack2bf_perm(float a, float b) {
    unsigned int u0 = __float_as_uint(a) + 0x8000u;
    unsigned int u1 = __float_as_uint(b) + 0x8000u;
    return __builtin_amdgcn_perm(u1, u0, 0x07060302u);
}

// pack two f32 -> bf16x2 (RNE, for outputs) [proven]
static __device__ __forceinline__ unsigned int pack2bf(float a, float b) {
    return (unsigned int)f2bf(a) | ((unsigned int)f2bf(b) << 16);
}

// v_permlane32_swap_b32 a, b : lanes[32:63] of a  <->  lanes[0:31] of b
#define PLSWAP(a, b) asm volatile("v_permlane32_swap_b32 %0, %1" : "+v"(a), "+v"(b))

// ---------------- fused cast kernel (x + 4 weights in one launch) ----------------
struct CastAll {
    const float* x;
    const float* w[4];
    unsigned short* xd;
    unsigned short* wd[4];
};

__global__ void cast_all_kernel(CastAll a) {
    int i = blockIdx.x * blockDim.x + threadIdx.x; // over float4 groups
    const float* s;
    unsigned short* d;
    int j;
    if (i < 2097152) { // x: 8M elems = 2M float4
        s = a.x; d = a.xd; j = i;
    } else {           // 4 weights: 256K float4 each
        int k = i - 2097152;
        int w = k >> 18;
        j = k & 262143;
        s = a.w[w]; d = a.wd[w];
    }
    float4 v = ((const float4*)s)[j];
    ushort4 o;
    o.x = f2bf(v.x); o.y = f2bf(v.y); o.z = f2bf(v.z); o.w = f2bf(v.w);
    ((ushort4*)d)[j] = o;
}

// ---------------- GEMM v11: 256x256 tile, 8 waves, early-issue double-buffer ----------------
// C[m,n] = sum_k A[m,k] * W[n,k]. A: [M,K] bf16; W: [N,K] bf16 (torch [out,in]).
// BM=BN=256, BK=64, 512 thr = 8 waves (2M x 4N), wave tile 128x64 (acc 4x2 of 32x32).
// LDS 128 KB: A/B tiles double-buffered. Pipeline: at top of tile t's compute,
// issue ALL 8 global_load_lds for tile t+1 into buf[d^1]; the only drain is the
// vmcnt(0) inside the single end-of-tile __syncthreads -- by then the loads have
// had a full tile of compute (32 MFMA + 24 ds_read_b128 per wave) to land.
// Race-free: reads of buf[d^1] ended before the PREVIOUS barrier; tile-t data was
// drained by the previous __syncthreads.
// LDS swizzle (proven): chunk c (16B) of row r stored at slot c ^ (r&7); staging
// lane ln loads global chunk ((ln&7)^lr) -> coalesced; frag reads conflict-free.
// VT2 (QKV launch): z==0 (Q) epilogue pre-scales by QSCL; z==2 (V) stores
// transposed Vt[(b*1024+col)][s].
template <typename OutT, bool VT2>
__global__ __launch_bounds__(512, 1) void gemm_bt(
    const unsigned short* __restrict__ A,
    const unsigned short* __restrict__ W0,
    const unsigned short* __restrict__ W1,
    const unsigned short* __restrict__ W2,
    OutT* __restrict__ C0, OutT* __restrict__ C1, OutT* __restrict__ C2,
    int M, int N, int K)
{
    __shared__ __align__(16) unsigned short At[2][256 * 64]; // 64 KB (double-buffered)
    __shared__ __align__(16) unsigned short Bt[2][256 * 64]; // 64 KB

    const unsigned short* W = (blockIdx.z == 0) ? W0 : ((blockIdx.z == 1) ? W1 : W2);
    OutT* C = (blockIdx.z == 0) ? C0 : ((blockIdx.z == 1) ? C1 : C2);

    const int m0 = blockIdx.x * 256;  // m-tile fastest: id%8 = m-tile%8 -> XCD locality
    const int n0 = blockIdx.y * 256;
    const int tid = threadIdx.x;
    const int wv = tid >> 6;       // 0..7
    const int ln = tid & 63;
    const int l31 = ln & 31;
    const int half = ln >> 5;
    const int wm = (wv >> 2) * 128; // wave row base (0/128)
    const int wn = (wv & 3) * 64;   // wave col base (0/64/128/192)

    floatx16 acc[4][2]; // [am][nt] 32x32 tiles
#pragma unroll
    for (int am = 0; am < 4; am++)
#pragma unroll
        for (int nt = 0; nt < 2; nt++)
#pragma unroll
            for (int e = 0; e < 16; e++) acc[am][nt][e] = 0.f;

    const int lr = ln >> 3;                   // lane row within 8-row/1KB chunk
    const int lc = (((ln & 7) ^ lr) * 8);     // swizzled global chunk (elements)
    const int sw = (l31 & 7);                 // frag-read swizzle key

    // stage one full K-tile (A 256x64 + B 256x64) into buffer d: 8 gload_lds/thread-pos
    // unit u: mat = u>>1 (0=A,1=B), hf = u&1; instr j: wave wv stages rows
    // [hf*128 + j*64 + wv*8, +8) (wave-uniform LDS base + lane*16).
#define STAGE(dbuf, k0)                                                                     \
    {                                                                                       \
        _Pragma("unroll")                                                                   \
        for (int u = 0; u < 4; u++) {                                                       \
            const unsigned short* src = (u < 2) ? A : W;                                    \
            unsigned short* dst = (u < 2) ? &At[dbuf][0] : &Bt[dbuf][0];                    \
            const int base0 = (u < 2) ? m0 : n0;                                            \
            const int hf = u & 1;                                                           \
            _Pragma("unroll")                                                               \
            for (int j = 0; j < 2; j++) {                                                   \
                const int rowb = hf * 128 + j * 64 + wv * 8;                                \
                const unsigned short* g = src + (size_t)(base0 + rowb + lr) * K + (k0) + lc;\
                __builtin_amdgcn_global_load_lds(                                           \
                    (const __attribute__((address_space(1))) void*)g,                       \
                    (__attribute__((address_space(3))) void*)&dst[rowb * 64], 16, 0, 0);    \
            }                                                                               \
        }                                                                                   \
    }

    STAGE(0, 0);
    __syncthreads(); // vmcnt(0) drain + barrier: tile 0 visible

    const int NT = K / 64;
    for (int t = 0; t < NT; t++) {
        const int d = t & 1;
        // early issue: next tile's loads fly under this tile's whole compute
        if (t + 1 < NT) STAGE(d ^ 1, (t + 1) * 64);

        // B fragments once (8 ds_read_b128), reused by both m-phases
        short8 bfr[2][4];
#pragma unroll
        for (int ks = 0; ks < 4; ks++) {
            const int slot = ((ks * 2 + half) ^ sw) * 8;
#pragma unroll
            for (int nt = 0; nt < 2; nt++)
                bfr[nt][ks] = *(const short8*)&Bt[d][(wn + nt * 32 + l31) * 64 + slot];
        }
        // two phases over m-halves of the wave tile (qm): 8 ds_reads + 16 MFMA each
#pragma unroll
        for (int qm = 0; qm < 2; qm++) {
            short8 af[2][4];
#pragma unroll
            for (int ks = 0; ks < 4; ks++) {
                const int slot = ((ks * 2 + half) ^ sw) * 8;
#pragma unroll
                for (int mt = 0; mt < 2; mt++)
                    af[mt][ks] = *(const short8*)&At[d][(wm + (qm * 2 + mt) * 32 + l31) * 64 + slot];
            }
            __builtin_amdgcn_s_setprio(1);
#pragma unroll
            for (int ks = 0; ks < 4; ks++)
#pragma unroll
                for (int mt = 0; mt < 2; mt++)
#pragma unroll
                    for (int nt = 0; nt < 2; nt++)
                        acc[qm * 2 + mt][nt] = __builtin_amdgcn_mfma_f32_32x32x16_bf16(
                            af[mt][ks], bfr[nt][ks], acc[qm * 2 + mt][nt], 0, 0, 0);
            __builtin_amdgcn_s_setprio(0);
        }
        __syncthreads(); // single drain point per K-tile: next tile staged + visible
    }
#undef STAGE

    // D layout (32x32): col = l31 (from B/n), row = (e&3) + 8*(e>>2) + 4*half
    const float esc = (VT2 && blockIdx.z == 0) ? QSCL : 1.0f; // fold softmax scale into Q

    if constexpr (VT2) {
        if (blockIdx.z == 2) {
            // transposed V store: Vt[(b*1024 + col)*2048 + s]; reg quad = 4 consec s
            unsigned short* Vt = (unsigned short*)C;
#pragma unroll
            for (int am = 0; am < 4; am++)
#pragma unroll
                for (int nt = 0; nt < 2; nt++)
#pragma unroll
                    for (int rg = 0; rg < 4; rg++) {
                        int col = n0 + wn + nt * 32 + l31;
                        int row0 = m0 + wm + am * 32 + 4 * half + 8 * rg; // %4==0
                        int bb = row0 >> 11, ss = row0 & 2047;
                        size_t addr = ((size_t)(bb * 1024 + col)) * 2048 + ss;
                        uint2 pk;
                        pk.x = pack2bf(acc[am][nt][4 * rg + 0], acc[am][nt][4 * rg + 1]);
                        pk.y = pack2bf(acc[am][nt][4 * rg + 2], acc[am][nt][4 * rg + 3]);
                        *(uint2*)(Vt + addr) = pk;
                    }
            return;
        }
    }

#pragma unroll
    for (int am = 0; am < 4; am++)
#pragma unroll
        for (int nt = 0; nt < 2; nt++)
#pragma unroll
            for (int rg = 0; rg < 4; rg++)
#pragma unroll
                for (int r = 0; r < 4; r++) {
                    int row = m0 + wm + am * 32 + 4 * half + 8 * rg + r;
                    int col = n0 + wn + nt * 32 + l31;
                    float v = acc[am][nt][4 * rg + r] * esc;
                    if constexpr (sizeof(OutT) == 2)
                        C[(size_t)row * N + col] = (OutT)f2bf(v);
                    else
                        C[(size_t)row * N + col] = v;
                }
}

// ---------------- flash attention (v9: 32 q/wave, 8 waves, XCD-colocated grid) ----------------
// UNCHANGED (87 us, occupancy 34%, FETCH 25.6MB).
__global__ __launch_bounds__(512, 4) void flash_attn(
    const unsigned short* __restrict__ Q,
    const unsigned short* __restrict__ K,
    const unsigned short* __restrict__ Vt,
    unsigned short* __restrict__ O)
{
    __shared__ __align__(16) unsigned short Kt[2][64 * 72]; // [buf][key][dk], +8 pad
    __shared__ __align__(16) unsigned short VT[2][64 * 72]; // [buf][dk][key], +8 pad

    const int pair = blockIdx.x; // 0..63: (b,h)
    const int h = pair & 15;
    const int b = pair >> 4;
    const int qt = blockIdx.y;   // 0..7
    const int tid = threadIdx.x;
    const int wv = tid >> 6;     // 0..7
    const int ln = tid & 63;
    const int l31 = ln & 31;
    const int half = ln >> 5;

    const size_t base = ((size_t)b * S_) * D_ + (size_t)h * DK_; // Q,K,O
    const size_t vtbase = ((size_t)(b * 1024 + h * 64)) * (size_t)S_;

    // Q B-fragment: lane l31 = q-row of this wave's 32-q slice, k-contig
    const int qrow = qt * 256 + wv * 32 + l31;
    short8 qf[4];
    {
        const unsigned short* qp = Q + base + (size_t)qrow * D_ + half * 8;
#pragma unroll
        for (int ks = 0; ks < 4; ks++) qf[ks] = *(const short8*)(qp + ks * 16);
    }

    floatx16 Oacc[2]; // [mt]
#pragma unroll
    for (int mt = 0; mt < 2; mt++)
#pragma unroll
        for (int e = 0; e < 16; e++) Oacc[mt][e] = 0.f;
    float l_i = 0.f;

    // staging: 512 threads, 8 lanes cover one 64-elem row (coalesced 128B);
    // each thread stages exactly one K chunk + one V chunk per tile.
    const int srow = tid >> 3;      // 0..63
    const int scol = (tid & 7) * 8; // col chunk
    const unsigned short* kp = K + base + (size_t)srow * D_ + scol;
    const unsigned short* vp = Vt + vtbase + (size_t)srow * S_ + scol;
    const int swo = srow * 72 + scol; // LDS write offset (elements)

    // prologue: stage tile 0 into registers
    short8 kr = *(const short8*)kp;
    short8 vr = *(const short8*)vp;
    kp += (size_t)64 * D_;
    vp += 64;

    for (int kt = 0; kt < S_ / 64; kt++) {
        const int cb = kt & 1;
        unsigned short* Kc = &Kt[cb][0];
        unsigned short* Vc = &VT[cb][0];
        // write staged regs into current buffer. Safe: all reads of this buffer
        // (iter kt-2's compute) finished before every thread reached barrier kt-1.
        *(short8*)&Kc[swo] = kr;
        *(short8*)&Vc[swo] = vr;
        __syncthreads(); // single barrier per iter: writes visible, prev-buf reads done

        // prefetch tile kt+1: issues now, lands during compute below
        if (kt < S_ / 64 - 1) {
            kr = *(const short8*)kp;
            vr = *(const short8*)vp;
            kp += (size_t)64 * D_;
            vp += 64;
        }

        uint2 run[2][4]; // [mt][g], keys mt*32 + 8g + 4*half + {0..3}

        // S^T = K Q^T per mt (32 keys x 32 q)
#pragma unroll
        for (int mt = 0; mt < 2; mt++) {
            floatx16 sac;
#pragma unroll
            for (int e = 0; e < 16; e++) sac[e] = 0.f;
            __builtin_amdgcn_s_setprio(1);
#pragma unroll
            for (int ks = 0; ks < 4; ks++) {
                short8 kf = *(const short8*)&Kc[(mt * 32 + l31) * 72 + ks * 16 + half * 8];
                sac = __builtin_amdgcn_mfma_f32_32x32x16_bf16(kf, qf[ks], sac, 0, 0, 0);
            }
            __builtin_amdgcn_s_setprio(0);
            // p = exp2(s); accumulate per-lane l partials; pack to bf16 pairs
#pragma unroll
            for (int g = 0; g < 4; g++) {
                float p0 = __builtin_amdgcn_exp2f(sac[4 * g + 0]);
                float p1 = __builtin_amdgcn_exp2f(sac[4 * g + 1]);
                float p2 = __builtin_amdgcn_exp2f(sac[4 * g + 2]);
                float p3 = __builtin_amdgcn_exp2f(sac[4 * g + 3]);
                l_i += (p0 + p1) + (p2 + p3);
                run[mt][g].x = pack2bf_perm(p0, p1);
                run[mt][g].y = pack2bf_perm(p2, p3);
            }
        }

        // rearrange runs into B-fragments (swap hi-lanes of even-g with lo-lanes of odd-g)
#pragma unroll
        for (int mt = 0; mt < 2; mt++)
#pragma unroll
            for (int t = 0; t < 2; t++) {
                PLSWAP(run[mt][2 * t].x, run[mt][2 * t + 1].x);
                PLSWAP(run[mt][2 * t].y, run[mt][2 * t + 1].y);
            }

        // O^T = V^T P^T
#pragma unroll
        for (int mt2 = 0; mt2 < 2; mt2++)
#pragma unroll
            for (int t = 0; t < 2; t++) {
                int ks = mt2 * 2 + t;
                uint4v u = {run[mt2][2 * t].x, run[mt2][2 * t].y,
                            run[mt2][2 * t + 1].x, run[mt2][2 * t + 1].y};
                short8 pf = __builtin_bit_cast(short8, u);
                __builtin_amdgcn_s_setprio(1);
#pragma unroll
                for (int mt = 0; mt < 2; mt++) {
                    short8 vf = *(const short8*)&Vc[(mt * 32 + l31) * 72 + ks * 16 + half * 8];
                    Oacc[mt] = __builtin_amdgcn_mfma_f32_32x32x16_bf16(vf, pf, Oacc[mt], 0, 0, 0);
                }
                __builtin_amdgcn_s_setprio(0);
            }
    }

    // epilogue: lanes (l, l+32) hold complementary key partials for the same q
    {
        float ls = l_i + __shfl_xor(l_i, 32);
        float inv = 1.0f / ls;
        const size_t orow = base + (size_t)qrow * D_;
#pragma unroll
        for (int mt = 0; mt < 2; mt++)
#pragma unroll
            for (int g = 0; g < 4; g++) {
                uint2 pk;
                pk.x = pack2bf(Oacc[mt][4 * g + 0] * inv, Oacc[mt][4 * g + 1] * inv);
                pk.y = pack2bf(Oacc[mt][4 * g + 2] * inv, Oacc[mt][4 * g + 3] * inv);
                *(uint2*)(O + orow + mt * 32 + 8 * g + 4 * half) = pk;
            }
    }
}

extern "C" void kernel_launch(void* const* d_in, const int* in_sizes, int n_in,
                              void* d_out, int out_size, void* d_ws, size_t ws_size,
                              hipStream_t stream) {
    const float* x  = (const float*)d_in[0];
    const float* Wq = (const float*)d_in[1];
    const float* Wk = (const float*)d_in[2];
    const float* Wv = (const float*)d_in[3];
    const float* Wo = (const float*)d_in[4];
    float* out = (float*)d_out;

    char* ws = (char*)d_ws;
    const size_t MB = 1024 * 1024;
    unsigned short* xb  = (unsigned short*)(ws);            // 16 MB
    unsigned short* wqb = (unsigned short*)(ws + 16 * MB);  // 2 MB each
    unsigned short* wkb = (unsigned short*)(ws + 18 * MB);
    unsigned short* wvb = (unsigned short*)(ws + 20 * MB);
    unsigned short* wob = (unsigned short*)(ws + 22 * MB);
    unsigned short* Qb  = (unsigned short*)(ws + 24 * MB);  // 16 MB
    unsigned short* Kb  = (unsigned short*)(ws + 40 * MB);
    unsigned short* Vtb = (unsigned short*)(ws + 56 * MB);  // V transposed [B*H*DK, S]
    unsigned short* Ob  = (unsigned short*)(ws);            // alias xb (dead after QKV GEMM)

    CastAll ca;
    ca.x = x; ca.xd = xb;
    ca.w[0] = Wq; ca.w[1] = Wk; ca.w[2] = Wv; ca.w[3] = Wo;
    ca.wd[0] = wqb; ca.wd[1] = wkb; ca.wd[2] = wvb; ca.wd[3] = wob;
    cast_all_kernel<<<12288, 256, 0, stream>>>(ca);

    // grid (m-tile, n-tile, z): id%8 = m-tile%8 -> XCD locality on A
    dim3 gq((B_ * S_) / 256, D_ / 256, 3); // (32, 4, 3) = 384 blocks x 512 thr
    gemm_bt<unsigned short, true><<<gq, 512, 0, stream>>>(
        xb, wqb, wkb, wvb, Qb, Kb, Vtb, B_ * S_, D_, D_);

    // grid (pair, qt): id%8 = pair%8 -> all qt-blocks of one (b,h) share an XCD
    dim3 gf(64, S_ / 256, 1); // (64, 8) = 512 blocks x 512 thr
    flash_attn<<<gf, 512, 0, stream>>>(Qb, Kb, Vtb, Ob);

    dim3 go((B_ * S_) / 256, D_ / 256, 1); // (32, 4) = 128 blocks, all-concurrent
    gemm_bt<float, false><<<go, 512, 0, stream>>>(
        Ob, wob, wob, wob, out, out, out, B_ * S_, D_, D_);
}

// Round 6
// 282.444 us; speedup vs baseline: 1.0300x; 1.0300x over previous
//
#include <hip/hip_runtime.h>
#include <hip/hip_bf16.h>

// Problem constants (fixed by reference)
#define B_ 4
#define S_ 2048
#define D_ 1024
#define H_ 16
#define DK_ 64

typedef __attribute__((ext_vector_type(8))) short short8;
typedef __attribute__((ext_vector_type(4))) float floatx4;
typedef __attribute__((ext_vector_type(16))) float floatx16;
typedef __attribute__((ext_vector_type(4))) unsigned int uint4v;

#define QSCL 0.1803368801111204f  // log2(e)/sqrt(DK): folded into Q in GEMM epilogue

// round-to-nearest-even f32 -> bf16 bits
static __device__ __forceinline__ unsigned short f2bf(float f) {
    unsigned int u = __float_as_uint(f);
    u += 0x7fffu + ((u >> 16) & 1u);
    return (unsigned short)(u >> 16);
}

// pack two f32 -> bf16x2, round-nearest-ties-up via v_perm_b32 (3 VALU ops) [proven]
static __device__ __forceinline__ unsigned int pack2bf_perm(float a, float b) {
    unsigned int u0 = __float_as_uint(a) + 0x8000u;
    unsigned int u1 = __float_as_uint(b) + 0x8000u;
    return __builtin_amdgcn_perm(u1, u0, 0x07060302u);
}

// pack two f32 -> bf16x2 (RNE, for outputs) [proven]
static __device__ __forceinline__ unsigned int pack2bf(float a, float b) {
    return (unsigned int)f2bf(a) | ((unsigned int)f2bf(b) << 16);
}

// v_permlane32_swap_b32 a, b : lanes[32:63] of a  <->  lanes[0:31] of b
#define PLSWAP(a, b) asm volatile("v_permlane32_swap_b32 %0, %1" : "+v"(a), "+v"(b))

// counted waitcnt (T4): N loads may stay in flight across the barrier
#define SW_VMCNT(N) asm volatile("s_waitcnt vmcnt(" #N ")" ::: "memory")

// ---------------- fused cast kernel (x + 4 weights in one launch) ----------------
struct CastAll {
    const float* x;
    const float* w[4];
    unsigned short* xd;
    unsigned short* wd[4];
};

__global__ void cast_all_kernel(CastAll a) {
    int i = blockIdx.x * blockDim.x + threadIdx.x; // over float4 groups
    const float* s;
    unsigned short* d;
    int j;
    if (i < 2097152) { // x: 8M elems = 2M float4
        s = a.x; d = a.xd; j = i;
    } else {           // 4 weights: 256K float4 each
        int k = i - 2097152;
        int w = k >> 18;
        j = k & 262143;
        s = a.w[w]; d = a.wd[w];
    }
    float4 v = ((const float4*)s)[j];
    ushort4 o;
    o.x = f2bf(v.x); o.y = f2bf(v.y); o.z = f2bf(v.z); o.w = f2bf(v.w);
    ((ushort4*)d)[j] = o;
}

// ---------------- GEMM v12: 256x128 tile, triple-buffer, counted-vmcnt depth-3 ----------------
// C[m,n] = sum_k A[m,k] * W[n,k]. A: [M,K] bf16; W: [N,K] bf16 (torch [out,in]).
// BM=256, BN=128, BK=64, 512 thr = 8 waves (4M x 2N), wave tile 64x64 (acc 2x2 of 32x32).
// LDS 144 KB: THREE buffers (A 32KB + B 16KB each). Pipeline depth 3:
//   iter t: STAGE tile t+2 -> buf[(t+2)%3]  (neither read now nor next iter)
//           ds-read tile t from buf[t%3]; 16 MFMA;
//           s_waitcnt vmcnt(6)  (t+1's 6 staging loads landed; t+2's 6 in flight)
//           s_barrier           (publish buf[(t+1)%3])
// NO vmcnt(0) drain in the main loop (T4, m218: counted-vs-drain0 +38-73%).
// Race-freedom: buf[(t+2)%3] was last READ at iter t-1; every wave's reads complete
// before it reaches barrier(t-1) (MFMA reg-deps force lgkmcnt), and STAGE issues
// after that barrier. vmcnt counts per-wave in issue order (m135).
// LDS swizzle (proven): chunk c (16B) of row r stored at slot c ^ (r&7); staging
// lane ln loads global chunk ((ln&7)^lr) -> coalesced; frag reads conflict-free.
// Grid (m-tile, n-tile, z): id%8 = m-tile%8 -> XCD L2 locality (A-chunk 2MB + W 2MB).
// QKV: 768 blocks = 3 full rounds @1 block/CU; O-proj: 256 blocks = 1 full round.
// VT2 (QKV launch): z==0 (Q) epilogue pre-scales by QSCL; z==2 (V) stores
// transposed Vt[(b*1024+col)][s].
template <typename OutT, bool VT2>
__global__ __launch_bounds__(512, 1) void gemm_bt(
    const unsigned short* __restrict__ A,
    const unsigned short* __restrict__ W0,
    const unsigned short* __restrict__ W1,
    const unsigned short* __restrict__ W2,
    OutT* __restrict__ C0, OutT* __restrict__ C1, OutT* __restrict__ C2,
    int M, int N, int K)
{
    __shared__ __align__(16) unsigned short At[3][256 * 64]; // 96 KB
    __shared__ __align__(16) unsigned short Bt[3][128 * 64]; // 48 KB

    const unsigned short* W = (blockIdx.z == 0) ? W0 : ((blockIdx.z == 1) ? W1 : W2);
    OutT* C = (blockIdx.z == 0) ? C0 : ((blockIdx.z == 1) ? C1 : C2);

    const int m0 = blockIdx.x * 256;  // m-tile fastest: id%8 = m-tile%8 -> XCD locality
    const int n0 = blockIdx.y * 128;
    const int tid = threadIdx.x;
    const int wv = tid >> 6;       // 0..7
    const int ln = tid & 63;
    const int l31 = ln & 31;
    const int half = ln >> 5;
    const int wm = (wv >> 1) * 64; // wave row base: 0/64/128/192
    const int wn = (wv & 1) * 64;  // wave col base: 0/64

    floatx16 acc[2][2]; // [mt][nt] 32x32 tiles (same as proven v10)
#pragma unroll
    for (int mt = 0; mt < 2; mt++)
#pragma unroll
        for (int nt = 0; nt < 2; nt++)
#pragma unroll
            for (int e = 0; e < 16; e++) acc[mt][nt][e] = 0.f;

    const int lr = ln >> 3;                   // lane row within 8-row/1KB chunk
    const int lc = (((ln & 7) ^ lr) * 8);     // swizzled global chunk (elements)
    const int sw = (l31 & 7);                 // frag-read swizzle key

    // stage one K-tile (A 256x64 + B 128x64 = 48KB) into buffer db:
    // per wave 4 A-chunks + 2 B-chunks (8 rows x 1KB each), wave-uniform LDS base.
#define STAGE(db, k0)                                                                       \
    {                                                                                       \
        _Pragma("unroll")                                                                   \
        for (int i = 0; i < 4; i++) {                                                       \
            const int rowb = wv * 32 + i * 8;                                               \
            const unsigned short* g = A + (size_t)(m0 + rowb + lr) * K + (k0) + lc;         \
            __builtin_amdgcn_global_load_lds(                                               \
                (const __attribute__((address_space(1))) void*)g,                           \
                (__attribute__((address_space(3))) void*)&At[db][rowb * 64], 16, 0, 0);     \
        }                                                                                   \
        _Pragma("unroll")                                                                   \
        for (int i = 0; i < 2; i++) {                                                       \
            const int rowb = wv * 16 + i * 8;                                               \
            const unsigned short* g = W + (size_t)(n0 + rowb + lr) * K + (k0) + lc;         \
            __builtin_amdgcn_global_load_lds(                                               \
                (const __attribute__((address_space(1))) void*)g,                           \
                (__attribute__((address_space(3))) void*)&Bt[db][rowb * 64], 16, 0, 0);     \
        }                                                                                   \
    }

    const int NT = K / 64; // 16
    // prologue: stage tiles 0 and 1 (12 loads in flight); wait tile 0 (6 remain)
    STAGE(0, 0);
    STAGE(1, 64);
    SW_VMCNT(6);
    __builtin_amdgcn_s_barrier();

    int cur = 0;
    for (int t = 0; t < NT; t++) {
        // issue tile t+2 into the buffer not read this iter or next
        if (t + 2 < NT) {
            int stg = cur + 2; if (stg >= 3) stg -= 3;
            STAGE(stg, (t + 2) * 64);
        }

        // ds-read tile t fragments (16 x ds_read_b128)
        short8 af[2][4], bfr[2][4];
#pragma unroll
        for (int ks = 0; ks < 4; ks++) {
            const int slot = ((ks * 2 + half) ^ sw) * 8;
#pragma unroll
            for (int nt = 0; nt < 2; nt++)
                bfr[nt][ks] = *(const short8*)&Bt[cur][(wn + nt * 32 + l31) * 64 + slot];
#pragma unroll
            for (int mt = 0; mt < 2; mt++)
                af[mt][ks] = *(const short8*)&At[cur][(wm + mt * 32 + l31) * 64 + slot];
        }

        __builtin_amdgcn_s_setprio(1);
#pragma unroll
        for (int ks = 0; ks < 4; ks++)
#pragma unroll
            for (int mt = 0; mt < 2; mt++)
#pragma unroll
                for (int nt = 0; nt < 2; nt++)
                    acc[mt][nt] = __builtin_amdgcn_mfma_f32_32x32x16_bf16(
                        af[mt][ks], bfr[nt][ks], acc[mt][nt], 0, 0, 0);
        __builtin_amdgcn_s_setprio(0);

        // publish tile t+1: its 6 loads (issued at iter t-1) must have landed.
        if (t + 1 < NT) {
            if (t + 2 < NT) { SW_VMCNT(6); } // t+2's 6 stay in flight
            else            { SW_VMCNT(0); } // tail: drain t+1
            __builtin_amdgcn_s_barrier();
        }
        cur = (cur == 2) ? 0 : cur + 1;
    }
#undef STAGE

    // D layout (32x32): col = l31 (from B/n), row = (e&3) + 8*(e>>2) + 4*half
    const float esc = (VT2 && blockIdx.z == 0) ? QSCL : 1.0f; // fold softmax scale into Q

    if constexpr (VT2) {
        if (blockIdx.z == 2) {
            // transposed V store: Vt[(b*1024 + col)*2048 + s]; reg quad = 4 consec s
            unsigned short* Vt = (unsigned short*)C;
#pragma unroll
            for (int mt = 0; mt < 2; mt++)
#pragma unroll
                for (int nt = 0; nt < 2; nt++)
#pragma unroll
                    for (int rg = 0; rg < 4; rg++) {
                        int col = n0 + wn + nt * 32 + l31;
                        int row0 = m0 + wm + mt * 32 + 4 * half + 8 * rg; // %4==0
                        int bb = row0 >> 11, ss = row0 & 2047;
                        size_t addr = ((size_t)(bb * 1024 + col)) * 2048 + ss;
                        uint2 pk;
                        pk.x = pack2bf(acc[mt][nt][4 * rg + 0], acc[mt][nt][4 * rg + 1]);
                        pk.y = pack2bf(acc[mt][nt][4 * rg + 2], acc[mt][nt][4 * rg + 3]);
                        *(uint2*)(Vt + addr) = pk;
                    }
            return;
        }
    }

#pragma unroll
    for (int mt = 0; mt < 2; mt++)
#pragma unroll
        for (int nt = 0; nt < 2; nt++)
#pragma unroll
            for (int rg = 0; rg < 4; rg++)
#pragma unroll
                for (int r = 0; r < 4; r++) {
                    int row = m0 + wm + mt * 32 + 4 * half + 8 * rg + r;
                    int col = n0 + wn + nt * 32 + l31;
                    float v = acc[mt][nt][4 * rg + r] * esc;
                    if constexpr (sizeof(OutT) == 2)
                        C[(size_t)row * N + col] = (OutT)f2bf(v);
                    else
                        C[(size_t)row * N + col] = v;
                }
}

// ---------------- flash attention (v9: 32 q/wave, 8 waves, XCD-colocated grid) ----------------
// UNCHANGED (88 us, occupancy 34%, FETCH 25.6MB).
__global__ __launch_bounds__(512, 4) void flash_attn(
    const unsigned short* __restrict__ Q,
    const unsigned short* __restrict__ K,
    const unsigned short* __restrict__ Vt,
    unsigned short* __restrict__ O)
{
    __shared__ __align__(16) unsigned short Kt[2][64 * 72]; // [buf][key][dk], +8 pad
    __shared__ __align__(16) unsigned short VT[2][64 * 72]; // [buf][dk][key], +8 pad

    const int pair = blockIdx.x; // 0..63: (b,h)
    const int h = pair & 15;
    const int b = pair >> 4;
    const int qt = blockIdx.y;   // 0..7
    const int tid = threadIdx.x;
    const int wv = tid >> 6;     // 0..7
    const int ln = tid & 63;
    const int l31 = ln & 31;
    const int half = ln >> 5;

    const size_t base = ((size_t)b * S_) * D_ + (size_t)h * DK_; // Q,K,O
    const size_t vtbase = ((size_t)(b * 1024 + h * 64)) * (size_t)S_;

    // Q B-fragment: lane l31 = q-row of this wave's 32-q slice, k-contig
    const int qrow = qt * 256 + wv * 32 + l31;
    short8 qf[4];
    {
        const unsigned short* qp = Q + base + (size_t)qrow * D_ + half * 8;
#pragma unroll
        for (int ks = 0; ks < 4; ks++) qf[ks] = *(const short8*)(qp + ks * 16);
    }

    floatx16 Oacc[2]; // [mt]
#pragma unroll
    for (int mt = 0; mt < 2; mt++)
#pragma unroll
        for (int e = 0; e < 16; e++) Oacc[mt][e] = 0.f;
    float l_i = 0.f;

    // staging: 512 threads, 8 lanes cover one 64-elem row (coalesced 128B);
    // each thread stages exactly one K chunk + one V chunk per tile.
    const int srow = tid >> 3;      // 0..63
    const int scol = (tid & 7) * 8; // col chunk
    const unsigned short* kp = K + base + (size_t)srow * D_ + scol;
    const unsigned short* vp = Vt + vtbase + (size_t)srow * S_ + scol;
    const int swo = srow * 72 + scol; // LDS write offset (elements)

    // prologue: stage tile 0 into registers
    short8 kr = *(const short8*)kp;
    short8 vr = *(const short8*)vp;
    kp += (size_t)64 * D_;
    vp += 64;

    for (int kt = 0; kt < S_ / 64; kt++) {
        const int cb = kt & 1;
        unsigned short* Kc = &Kt[cb][0];
        unsigned short* Vc = &VT[cb][0];
        // write staged regs into current buffer. Safe: all reads of this buffer
        // (iter kt-2's compute) finished before every thread reached barrier kt-1.
        *(short8*)&Kc[swo] = kr;
        *(short8*)&Vc[swo] = vr;
        __syncthreads(); // single barrier per iter: writes visible, prev-buf reads done

        // prefetch tile kt+1: issues now, lands during compute below
        if (kt < S_ / 64 - 1) {
            kr = *(const short8*)kp;
            vr = *(const short8*)vp;
            kp += (size_t)64 * D_;
            vp += 64;
        }

        uint2 run[2][4]; // [mt][g], keys mt*32 + 8g + 4*half + {0..3}

        // S^T = K Q^T per mt (32 keys x 32 q)
#pragma unroll
        for (int mt = 0; mt < 2; mt++) {
            floatx16 sac;
#pragma unroll
            for (int e = 0; e < 16; e++) sac[e] = 0.f;
            __builtin_amdgcn_s_setprio(1);
#pragma unroll
            for (int ks = 0; ks < 4; ks++) {
                short8 kf = *(const short8*)&Kc[(mt * 32 + l31) * 72 + ks * 16 + half * 8];
                sac = __builtin_amdgcn_mfma_f32_32x32x16_bf16(kf, qf[ks], sac, 0, 0, 0);
            }
            __builtin_amdgcn_s_setprio(0);
            // p = exp2(s); accumulate per-lane l partials; pack to bf16 pairs
#pragma unroll
            for (int g = 0; g < 4; g++) {
                float p0 = __builtin_amdgcn_exp2f(sac[4 * g + 0]);
                float p1 = __builtin_amdgcn_exp2f(sac[4 * g + 1]);
                float p2 = __builtin_amdgcn_exp2f(sac[4 * g + 2]);
                float p3 = __builtin_amdgcn_exp2f(sac[4 * g + 3]);
                l_i += (p0 + p1) + (p2 + p3);
                run[mt][g].x = pack2bf_perm(p0, p1);
                run[mt][g].y = pack2bf_perm(p2, p3);
            }
        }

        // rearrange runs into B-fragments (swap hi-lanes of even-g with lo-lanes of odd-g)
#pragma unroll
        for (int mt = 0; mt < 2; mt++)
#pragma unroll
            for (int t = 0; t < 2; t++) {
                PLSWAP(run[mt][2 * t].x, run[mt][2 * t + 1].x);
                PLSWAP(run[mt][2 * t].y, run[mt][2 * t + 1].y);
            }

        // O^T = V^T P^T
#pragma unroll
        for (int mt2 = 0; mt2 < 2; mt2++)
#pragma unroll
            for (int t = 0; t < 2; t++) {
                int ks = mt2 * 2 + t;
                uint4v u = {run[mt2][2 * t].x, run[mt2][2 * t].y,
                            run[mt2][2 * t + 1].x, run[mt2][2 * t + 1].y};
                short8 pf = __builtin_bit_cast(short8, u);
                __builtin_amdgcn_s_setprio(1);
#pragma unroll
                for (int mt = 0; mt < 2; mt++) {
                    short8 vf = *(const short8*)&Vc[(mt * 32 + l31) * 72 + ks * 16 + half * 8];
                    Oacc[mt] = __builtin_amdgcn_mfma_f32_32x32x16_bf16(vf, pf, Oacc[mt], 0, 0, 0);
                }
                __builtin_amdgcn_s_setprio(0);
            }
    }

    // epilogue: lanes (l, l+32) hold complementary key partials for the same q
    {
        float ls = l_i + __shfl_xor(l_i, 32);
        float inv = 1.0f / ls;
        const size_t orow = base + (size_t)qrow * D_;
#pragma unroll
        for (int mt = 0; mt < 2; mt++)
#pragma unroll
            for (int g = 0; g < 4; g++) {
                uint2 pk;
                pk.x = pack2bf(Oacc[mt][4 * g + 0] * inv, Oacc[mt][4 * g + 1] * inv);
                pk.y = pack2bf(Oacc[mt][4 * g + 2] * inv, Oacc[mt][4 * g + 3] * inv);
                *(uint2*)(O + orow + mt * 32 + 8 * g + 4 * half) = pk;
            }
    }
}

extern "C" void kernel_launch(void* const* d_in, const int* in_sizes, int n_in,
                              void* d_out, int out_size, void* d_ws, size_t ws_size,
                              hipStream_t stream) {
    const float* x  = (const float*)d_in[0];
    const float* Wq = (const float*)d_in[1];
    const float* Wk = (const float*)d_in[2];
    const float* Wv = (const float*)d_in[3];
    const float* Wo = (const float*)d_in[4];
    float* out = (float*)d_out;

    char* ws = (char*)d_ws;
    const size_t MB = 1024 * 1024;
    unsigned short* xb  = (unsigned short*)(ws);            // 16 MB
    unsigned short* wqb = (unsigned short*)(ws + 16 * MB);  // 2 MB each
    unsigned short* wkb = (unsigned short*)(ws + 18 * MB);
    unsigned short* wvb = (unsigned short*)(ws + 20 * MB);
    unsigned short* wob = (unsigned short*)(ws + 22 * MB);
    unsigned short* Qb  = (unsigned short*)(ws + 24 * MB);  // 16 MB
    unsigned short* Kb  = (unsigned short*)(ws + 40 * MB);
    unsigned short* Vtb = (unsigned short*)(ws + 56 * MB);  // V transposed [B*H*DK, S]
    unsigned short* Ob  = (unsigned short*)(ws);            // alias xb (dead after QKV GEMM)

    CastAll ca;
    ca.x = x; ca.xd = xb;
    ca.w[0] = Wq; ca.w[1] = Wk; ca.w[2] = Wv; ca.w[3] = Wo;
    ca.wd[0] = wqb; ca.wd[1] = wkb; ca.wd[2] = wvb; ca.wd[3] = wob;
    cast_all_kernel<<<12288, 256, 0, stream>>>(ca);

    // grid (m-tile, n-tile, z): id%8 = m-tile%8 -> XCD locality on A
    dim3 gq((B_ * S_) / 256, D_ / 128, 3); // (32, 8, 3) = 768 blocks = 3 full rounds
    gemm_bt<unsigned short, true><<<gq, 512, 0, stream>>>(
        xb, wqb, wkb, wvb, Qb, Kb, Vtb, B_ * S_, D_, D_);

    // grid (pair, qt): id%8 = pair%8 -> all qt-blocks of one (b,h) share an XCD
    dim3 gf(64, S_ / 256, 1); // (64, 8) = 512 blocks x 512 thr
    flash_attn<<<gf, 512, 0, stream>>>(Qb, Kb, Vtb, Ob);

    dim3 go((B_ * S_) / 256, D_ / 128, 1); // (32, 8) = 256 blocks = 1 full round
    gemm_bt<float, false><<<go, 512, 0, stream>>>(
        Ob, wob, wob, wob, out, out, out, B_ * S_, D_, D_);
}

// Round 7
// 272.044 us; speedup vs baseline: 1.0694x; 1.0382x over previous
//
#include <hip/hip_runtime.h>
#include <hip/hip_bf16.h>

// Problem constants (fixed by reference)
#define B_ 4
#define S_ 2048
#define D_ 1024
#define H_ 16
#define DK_ 64

typedef __attribute__((ext_vector_type(8))) short short8;
typedef __attribute__((ext_vector_type(4))) float floatx4;
typedef __attribute__((ext_vector_type(16))) float floatx16;
typedef __attribute__((ext_vector_type(4))) unsigned int uint4v;

#define QSCL 0.1803368801111204f  // log2(e)/sqrt(DK): folded into Q in GEMM epilogue

// round-to-nearest-even f32 -> bf16 bits
static __device__ __forceinline__ unsigned short f2bf(float f) {
    unsigned int u = __float_as_uint(f);
    u += 0x7fffu + ((u >> 16) & 1u);
    return (unsigned short)(u >> 16);
}

// pack two f32 -> bf16x2, round-nearest-ties-up via v_perm_b32 (3 VALU ops) [proven]
static __device__ __forceinline__ unsigned int pack2bf_perm(float a, float b) {
    unsigned int u0 = __float_as_uint(a) + 0x8000u;
    unsigned int u1 = __float_as_uint(b) + 0x8000u;
    return __builtin_amdgcn_perm(u1, u0, 0x07060302u);
}

// pack two f32 -> bf16x2 (RNE, for outputs) [proven]
static __device__ __forceinline__ unsigned int pack2bf(float a, float b) {
    return (unsigned int)f2bf(a) | ((unsigned int)f2bf(b) << 16);
}

// v_permlane32_swap_b32 a, b : lanes[32:63] of a  <->  lanes[0:31] of b
#define PLSWAP(a, b) asm volatile("v_permlane32_swap_b32 %0, %1" : "+v"(a), "+v"(b))

// ---------------- fused cast kernel (x + 4 weights in one launch) ----------------
struct CastAll {
    const float* x;
    const float* w[4];
    unsigned short* xd;
    unsigned short* wd[4];
};

__global__ void cast_all_kernel(CastAll a) {
    int i = blockIdx.x * blockDim.x + threadIdx.x; // over float4 groups
    const float* s;
    unsigned short* d;
    int j;
    if (i < 2097152) { // x: 8M elems = 2M float4
        s = a.x; d = a.xd; j = i;
    } else {           // 4 weights: 256K float4 each
        int k = i - 2097152;
        int w = k >> 18;
        j = k & 262143;
        s = a.w[w]; d = a.wd[w];
    }
    float4 v = ((const float4*)s)[j];
    ushort4 o;
    o.x = f2bf(v.x); o.y = f2bf(v.y); o.z = f2bf(v.z); o.w = f2bf(v.w);
    ((ushort4*)d)[j] = o;
}

// ---------------- GEMM (v10, proven best: 128x128, 2-barrier, multi-block/CU) ----------------
// C[m,n] = sum_k A[m,k] * W[n,k]. A: [M,K] bf16; W: [N,K] bf16 (torch [out,in]).
// 128x128 tile, BK=64, 256 threads, global_load_lds width=16.
// LDS swizzle: chunk c (16B) of row r stored at slot c ^ (r&7); staging lane ln
// loads global chunk (ln&7)^(lr) -> coalesced; frag reads conflict-free.
// Grid (m-tile, n-tile, z): id%8 = m-tile%8 -> XCD L2 locality on A.
// VT2 (QKV launch): z==0 (Q) epilogue pre-scales by QSCL; z==2 (V) stores
// transposed Vt[(b*1024+col)][s].
template <typename OutT, bool VT2>
__global__ __launch_bounds__(256) void gemm_bt(
    const unsigned short* __restrict__ A,
    const unsigned short* __restrict__ W0,
    const unsigned short* __restrict__ W1,
    const unsigned short* __restrict__ W2,
    OutT* __restrict__ C0, OutT* __restrict__ C1, OutT* __restrict__ C2,
    int M, int N, int K)
{
    __shared__ __align__(16) unsigned short At[128 * 64]; // [row][slot^swizzle], NO pad
    __shared__ __align__(16) unsigned short Bt[128 * 64];

    const unsigned short* W = (blockIdx.z == 0) ? W0 : ((blockIdx.z == 1) ? W1 : W2);
    OutT* C = (blockIdx.z == 0) ? C0 : ((blockIdx.z == 1) ? C1 : C2);

    const int m0 = blockIdx.x * 128;  // m-tile fastest: id%8 = m-tile%8 -> XCD locality
    const int n0 = blockIdx.y * 128;
    const int wv = threadIdx.x >> 6;
    const int ln = threadIdx.x & 63;
    const int l31 = ln & 31;
    const int half = ln >> 5;
    const int wm = (wv >> 1) * 64; // wave's 64x64 quadrant
    const int wn = (wv & 1) * 64;

    floatx16 acc[2][2]; // [mt][nt] 32x32 tiles
#pragma unroll
    for (int mt = 0; mt < 2; mt++)
#pragma unroll
        for (int nt = 0; nt < 2; nt++)
#pragma unroll
            for (int e = 0; e < 16; e++) acc[mt][nt][e] = 0.f;

    const int lr = ln >> 3;                   // lane row within 8-row/1KB chunk
    const int lc = (((ln & 7) ^ lr) * 8);     // swizzled global chunk (elements)
    const int sw = (l31 & 7);                 // frag-read swizzle key

    for (int k0 = 0; k0 < K; k0 += 64) {
        __syncthreads(); // prior iter's LDS reads done before overwrite
#pragma unroll
        for (int c = 0; c < 4; c++) {
            int rowA = wv * 32 + c * 8;
            const unsigned short* gA = A + (size_t)(m0 + rowA + lr) * K + k0 + lc;
            __builtin_amdgcn_global_load_lds(
                (const __attribute__((address_space(1))) void*)gA,
                (__attribute__((address_space(3))) void*)&At[rowA * 64], 16, 0, 0);
            const unsigned short* gB = W + (size_t)(n0 + rowA + lr) * K + k0 + lc;
            __builtin_amdgcn_global_load_lds(
                (const __attribute__((address_space(1))) void*)gB,
                (__attribute__((address_space(3))) void*)&Bt[rowA * 64], 16, 0, 0);
        }
        __syncthreads(); // drains vmcnt (compiler emits waitcnt before barrier)

#pragma unroll
        for (int ks = 0; ks < 4; ks++) {
            const int slot = ((ks * 2 + half) ^ sw) * 8;
            short8 af[2], bf[2];
#pragma unroll
            for (int mt = 0; mt < 2; mt++)
                af[mt] = *(const short8*)&At[(wm + mt * 32 + l31) * 64 + slot];
#pragma unroll
            for (int nt = 0; nt < 2; nt++)
                bf[nt] = *(const short8*)&Bt[(wn + nt * 32 + l31) * 64 + slot];
#pragma unroll
            for (int mt = 0; mt < 2; mt++)
#pragma unroll
                for (int nt = 0; nt < 2; nt++)
                    acc[mt][nt] = __builtin_amdgcn_mfma_f32_32x32x16_bf16(af[mt], bf[nt], acc[mt][nt], 0, 0, 0);
        }
    }

    // D layout (32x32): col = l31 (from B/n), row = (e&3) + 8*(e>>2) + 4*half
    const float esc = (VT2 && blockIdx.z == 0) ? QSCL : 1.0f; // fold softmax scale into Q

    if constexpr (VT2) {
        if (blockIdx.z == 2) {
            // transposed V store: Vt[(b*1024 + col)*2048 + s]; reg quad = 4 consec s
            unsigned short* Vt = (unsigned short*)C;
#pragma unroll
            for (int mt = 0; mt < 2; mt++)
#pragma unroll
                for (int nt = 0; nt < 2; nt++)
#pragma unroll
                    for (int rg = 0; rg < 4; rg++) {
                        int col = n0 + wn + nt * 32 + l31;
                        int row0 = m0 + wm + mt * 32 + 4 * half + 8 * rg; // %4==0
                        int bb = row0 >> 11, ss = row0 & 2047;
                        size_t addr = ((size_t)(bb * 1024 + col)) * 2048 + ss;
                        uint2 pk;
                        pk.x = pack2bf(acc[mt][nt][4 * rg + 0], acc[mt][nt][4 * rg + 1]);
                        pk.y = pack2bf(acc[mt][nt][4 * rg + 2], acc[mt][nt][4 * rg + 3]);
                        *(uint2*)(Vt + addr) = pk;
                    }
            return;
        }
    }

#pragma unroll
    for (int mt = 0; mt < 2; mt++)
#pragma unroll
        for (int nt = 0; nt < 2; nt++)
#pragma unroll
            for (int rg = 0; rg < 4; rg++)
#pragma unroll
                for (int r = 0; r < 4; r++) {
                    int row = m0 + wm + mt * 32 + 4 * half + 8 * rg + r;
                    int col = n0 + wn + nt * 32 + l31;
                    float v = acc[mt][nt][4 * rg + r] * esc;
                    if constexpr (sizeof(OutT) == 2)
                        C[(size_t)row * N + col] = (OutT)f2bf(v);
                    else
                        C[(size_t)row * N + col] = v;
                }
}

// ---------------- flash attention (v13: intra-block split-K, 16 waves, 100% occupancy) ----------------
// Q (pre-scaled by QSCL), K, O: [B*S, D] bf16; Vt: [B*H*DK, S] bf16.
// v13 vs v9: wave count was grid-capped at 16 waves/CU (VALUBusy 50%, all pipes
// half-idle). Block -> 1024 thr = 16 waves: group wg=0 processes keys 0..1023,
// wg=1 keys 1024..2047; each group has its own double-buffered K/V LDS half
// (72 KB total -> 2 blocks/CU, grid 512 = exact fit) => 8192 waves = 32/CU = 100%.
// Inner loop identical to proven v9 (16 iters, offset bases). Combine via LDS:
// group 1 writes 32-f32 partial + l at stride 33 (conflict-free); group 0 adds,
// normalizes once, stores. f32 partials throughout -> numerics unchanged.
__global__ __launch_bounds__(1024, 2) void flash_attn(
    const unsigned short* __restrict__ Q,
    const unsigned short* __restrict__ K,
    const unsigned short* __restrict__ Vt,
    unsigned short* __restrict__ O)
{
    // [wg][buf][kv][64*72] staging; reused as f32 exchange buffer in epilogue
    __shared__ __align__(16) unsigned short KVs[2][2][2][64 * 72]; // 73728 B

    const int pair = blockIdx.x; // 0..63: (b,h); id%8 = pair%8 -> XCD colocation
    const int h = pair & 15;
    const int b = pair >> 4;
    const int qt = blockIdx.y;   // 0..7
    const int tid = threadIdx.x; // 0..1023
    const int wv = tid >> 6;     // 0..15
    const int wg = wv >> 3;      // key-split group: 0 = keys[0,1024), 1 = keys[1024,2048)
    const int wl = wv & 7;       // wave within group
    const int ln = tid & 63;
    const int l31 = ln & 31;
    const int half = ln >> 5;

    const size_t base = ((size_t)b * S_) * D_ + (size_t)h * DK_; // Q,K,O
    const size_t vtbase = ((size_t)(b * 1024 + h * 64)) * (size_t)S_;

    // Q B-fragment: lane l31 = q-row of this wave's 32-q slice (same rows for both groups)
    const int qrow = qt * 256 + wl * 32 + l31;
    short8 qf[4];
    {
        const unsigned short* qp = Q + base + (size_t)qrow * D_ + half * 8;
#pragma unroll
        for (int ks = 0; ks < 4; ks++) qf[ks] = *(const short8*)(qp + ks * 16);
    }

    floatx16 Oacc[2]; // [mt]
#pragma unroll
    for (int mt = 0; mt < 2; mt++)
#pragma unroll
        for (int e = 0; e < 16; e++) Oacc[mt][e] = 0.f;
    float l_i = 0.f;

    // staging: each group's 512 threads stage that group's K/V tile (8 lanes/row)
    const int gtid = tid & 511;
    const int srow = gtid >> 3;      // 0..63
    const int scol = (gtid & 7) * 8; // col chunk
    const unsigned short* kp = K + base + (size_t)(wg * 1024 + srow) * D_ + scol;     // K rows = keys
    const unsigned short* vp = Vt + vtbase + (size_t)srow * S_ + wg * 1024 + scol;    // Vt cols = keys
    const int swo = srow * 72 + scol; // LDS write offset (elements)

    // prologue: stage this group's tile 0 into registers
    short8 kr = *(const short8*)kp;
    short8 vr = *(const short8*)vp;
    kp += (size_t)64 * D_;
    vp += 64;

    for (int kt = 0; kt < 16; kt++) {
        const int cb = kt & 1;
        unsigned short* Kc = &KVs[wg][cb][0][0];
        unsigned short* Vc = &KVs[wg][cb][1][0];
        // safe: all reads of this buffer (iter kt-2) finished before barrier kt-1
        *(short8*)&Kc[swo] = kr;
        *(short8*)&Vc[swo] = vr;
        __syncthreads(); // single barrier per iter (all 16 waves, lockstep loop)

        // prefetch tile kt+1 within this group's key range
        if (kt < 15) {
            kr = *(const short8*)kp;
            vr = *(const short8*)vp;
            kp += (size_t)64 * D_;
            vp += 64;
        }

        uint2 run[2][4]; // [mt][g], keys mt*32 + 8g + 4*half + {0..3}

        // S^T = K Q^T per mt (32 keys x 32 q)
#pragma unroll
        for (int mt = 0; mt < 2; mt++) {
            floatx16 sac;
#pragma unroll
            for (int e = 0; e < 16; e++) sac[e] = 0.f;
            __builtin_amdgcn_s_setprio(1);
#pragma unroll
            for (int ks = 0; ks < 4; ks++) {
                short8 kf = *(const short8*)&Kc[(mt * 32 + l31) * 72 + ks * 16 + half * 8];
                sac = __builtin_amdgcn_mfma_f32_32x32x16_bf16(kf, qf[ks], sac, 0, 0, 0);
            }
            __builtin_amdgcn_s_setprio(0);
            // p = exp2(s); accumulate per-lane l partials; pack to bf16 pairs
#pragma unroll
            for (int g = 0; g < 4; g++) {
                float p0 = __builtin_amdgcn_exp2f(sac[4 * g + 0]);
                float p1 = __builtin_amdgcn_exp2f(sac[4 * g + 1]);
                float p2 = __builtin_amdgcn_exp2f(sac[4 * g + 2]);
                float p3 = __builtin_amdgcn_exp2f(sac[4 * g + 3]);
                l_i += (p0 + p1) + (p2 + p3);
                run[mt][g].x = pack2bf_perm(p0, p1);
                run[mt][g].y = pack2bf_perm(p2, p3);
            }
        }

        // rearrange runs into B-fragments (swap hi-lanes of even-g with lo-lanes of odd-g)
#pragma unroll
        for (int mt = 0; mt < 2; mt++)
#pragma unroll
            for (int t = 0; t < 2; t++) {
                PLSWAP(run[mt][2 * t].x, run[mt][2 * t + 1].x);
                PLSWAP(run[mt][2 * t].y, run[mt][2 * t + 1].y);
            }

        // O^T = V^T P^T
#pragma unroll
        for (int mt2 = 0; mt2 < 2; mt2++)
#pragma unroll
            for (int t = 0; t < 2; t++) {
                int ks = mt2 * 2 + t;
                uint4v u = {run[mt2][2 * t].x, run[mt2][2 * t].y,
                            run[mt2][2 * t + 1].x, run[mt2][2 * t + 1].y};
                short8 pf = __builtin_bit_cast(short8, u);
                __builtin_amdgcn_s_setprio(1);
#pragma unroll
                for (int mt = 0; mt < 2; mt++) {
                    short8 vf = *(const short8*)&Vc[(mt * 32 + l31) * 72 + ks * 16 + half * 8];
                    Oacc[mt] = __builtin_amdgcn_mfma_f32_32x32x16_bf16(vf, pf, Oacc[mt], 0, 0, 0);
                }
                __builtin_amdgcn_s_setprio(0);
            }
    }

    // ---- split-K combine: group 1 -> LDS, group 0 adds + normalizes + stores ----
    __syncthreads(); // all compute reads of KVs done
    float* ex = (float*)&KVs[0][0][0][0]; // 8 waves x 64 lanes x 33 f32 = 67584 B
    const int idx = (wl * 64 + ln) * 33;  // stride 33 -> bank-conflict-free
    if (wg == 1) {
        float ls1 = l_i + __shfl_xor(l_i, 32);
#pragma unroll
        for (int mt = 0; mt < 2; mt++)
#pragma unroll
            for (int e = 0; e < 16; e++) ex[idx + mt * 16 + e] = Oacc[mt][e];
        ex[idx + 32] = ls1;
    }
    __syncthreads();
    if (wg == 0) {
        float ls = l_i + __shfl_xor(l_i, 32);
        float inv = 1.0f / (ls + ex[idx + 32]);
        const size_t orow = base + (size_t)qrow * D_;
#pragma unroll
        for (int mt = 0; mt < 2; mt++)
#pragma unroll
            for (int g = 0; g < 4; g++) {
                float o0 = (Oacc[mt][4 * g + 0] + ex[idx + mt * 16 + 4 * g + 0]) * inv;
                float o1 = (Oacc[mt][4 * g + 1] + ex[idx + mt * 16 + 4 * g + 1]) * inv;
                float o2 = (Oacc[mt][4 * g + 2] + ex[idx + mt * 16 + 4 * g + 2]) * inv;
                float o3 = (Oacc[mt][4 * g + 3] + ex[idx + mt * 16 + 4 * g + 3]) * inv;
                uint2 pk;
                pk.x = pack2bf(o0, o1);
                pk.y = pack2bf(o2, o3);
                *(uint2*)(O + orow + mt * 32 + 8 * g + 4 * half) = pk;
            }
    }
}

extern "C" void kernel_launch(void* const* d_in, const int* in_sizes, int n_in,
                              void* d_out, int out_size, void* d_ws, size_t ws_size,
                              hipStream_t stream) {
    const float* x  = (const float*)d_in[0];
    const float* Wq = (const float*)d_in[1];
    const float* Wk = (const float*)d_in[2];
    const float* Wv = (const float*)d_in[3];
    const float* Wo = (const float*)d_in[4];
    float* out = (float*)d_out;

    char* ws = (char*)d_ws;
    const size_t MB = 1024 * 1024;
    unsigned short* xb  = (unsigned short*)(ws);            // 16 MB
    unsigned short* wqb = (unsigned short*)(ws + 16 * MB);  // 2 MB each
    unsigned short* wkb = (unsigned short*)(ws + 18 * MB);
    unsigned short* wvb = (unsigned short*)(ws + 20 * MB);
    unsigned short* wob = (unsigned short*)(ws + 22 * MB);
    unsigned short* Qb  = (unsigned short*)(ws + 24 * MB);  // 16 MB
    unsigned short* Kb  = (unsigned short*)(ws + 40 * MB);
    unsigned short* Vtb = (unsigned short*)(ws + 56 * MB);  // V transposed [B*H*DK, S]
    unsigned short* Ob  = (unsigned short*)(ws);            // alias xb (dead after QKV GEMM)

    CastAll ca;
    ca.x = x; ca.xd = xb;
    ca.w[0] = Wq; ca.w[1] = Wk; ca.w[2] = Wv; ca.w[3] = Wo;
    ca.wd[0] = wqb; ca.wd[1] = wkb; ca.wd[2] = wvb; ca.wd[3] = wob;
    cast_all_kernel<<<12288, 256, 0, stream>>>(ca);

    // grid (m-tile, n-tile, z): id%8 = m-tile%8 -> XCD locality on A (proven v10)
    dim3 gq((B_ * S_) / 128, D_ / 128, 3); // (64, 8, 3)
    gemm_bt<unsigned short, true><<<gq, 256, 0, stream>>>(
        xb, wqb, wkb, wvb, Qb, Kb, Vtb, B_ * S_, D_, D_);

    // grid (pair, qt): id%8 = pair%8 -> all qt-blocks of one (b,h) share an XCD
    dim3 gf(64, S_ / 256, 1); // (64, 8) = 512 blocks x 1024 thr (16 waves, split-K)
    flash_attn<<<gf, 1024, 0, stream>>>(Qb, Kb, Vtb, Ob);

    dim3 go((B_ * S_) / 128, D_ / 128, 1); // (64, 8)
    gemm_bt<float, false><<<go, 256, 0, stream>>>(
        Ob, wob, wob, wob, out, out, out, B_ * S_, D_, D_);
}